// Round 6
// baseline (690.285 us; speedup 1.0000x reference)
//
#include <hip/hip_runtime.h>

#define D_G   512
#define D_H   1024
#define D_OUT 512
#define BATCH 64
#define LAMv  0.95f
#define ETAv  0.5f

// ---------------------------------------------------------------------------
// ws layout (floats):
//   hist : 15 * 65536   (h after each gated timestep t=0..14)
//   hbp  : 8  * 65536   (8-way k-split partial h@Wh^T, summed in refine)
//   zg   : 16 * 65536   (z_t @ Wg^T + b_h for all t -- input-only, hoisted)
//   hfin : 65536
//   predp: 4 * 32768    (4-way k-split partial head, summed in loss)
// total ~11 MB
// ---------------------------------------------------------------------------

#define FMA4(A, V) \
  A.x = fmaf(w.x, V.x, A.x); A.y = fmaf(w.y, V.y, A.y); \
  A.z = fmaf(w.z, V.z, A.z); A.w = fmaf(w.w, V.w, A.w);

// zg[t][b][i] = z[t][b][:] . Wg[i][:] + bh[i]     (independent of recurrence)
// grid (16 i, 4 by, 16 t) = 1024 blocks, 256 thr. Thread: row i (lane),
// 4 batches (by*16 + wid*4 + q). Wg re-read 4x/t (vs 8x) -> 128 MB total,
// below the ~6.8 us VALU floor so loads stay hidden.
__global__ __launch_bounds__(256) void k_zg(const float* __restrict__ z,
                                            const float* __restrict__ Wg,
                                            const float* __restrict__ bh,
                                            float* __restrict__ zg) {
  const int lane = threadIdx.x & 63;
  const int wid  = threadIdx.x >> 6;
  const int i  = blockIdx.x * 64 + lane;
  const int bb = blockIdx.y * 16 + wid * 4;     // 4 consecutive batches
  const int t  = blockIdx.z;
  const float4* wr = (const float4*)(Wg + (size_t)i * D_G);
  const float4* z0 = (const float4*)(z + ((size_t)t * BATCH + bb + 0) * D_G);
  const float4* z1 = (const float4*)(z + ((size_t)t * BATCH + bb + 1) * D_G);
  const float4* z2 = (const float4*)(z + ((size_t)t * BATCH + bb + 2) * D_G);
  const float4* z3 = (const float4*)(z + ((size_t)t * BATCH + bb + 3) * D_G);
  float4 A0 = {0,0,0,0}, A1 = {0,0,0,0}, A2 = {0,0,0,0}, A3 = {0,0,0,0};
#pragma unroll 4
  for (int j = 0; j < D_G/4; ++j) {
    float4 w = wr[j];
    float4 x0 = z0[j], x1 = z1[j], x2 = z2[j], x3 = z3[j];
    FMA4(A0, x0) FMA4(A1, x1) FMA4(A2, x2) FMA4(A3, x3)
  }
  float bias = bh[i];
  float* o = zg + (size_t)t * (BATCH * D_H);
  o[(size_t)(bb+0)*D_H + i] = (A0.x+A0.y)+(A0.z+A0.w) + bias;
  o[(size_t)(bb+1)*D_H + i] = (A1.x+A1.y)+(A1.z+A1.w) + bias;
  o[(size_t)(bb+2)*D_H + i] = (A2.x+A2.y)+(A2.z+A2.w) + bias;
  o[(size_t)(bb+3)*D_H + i] = (A3.x+A3.y)+(A3.z+A3.w) + bias;
}

// Partial h@Wh^T: outp[k][b][i] = sum_{j in k-th eighth} Wh[i][j] hprev[b][j]
// grid (16 i, 4 by, 8 k) = 512 blocks, 256 thr, 4 batches/thread.
// Wh re-read 4x (16 MB/step ~0.46us L2) < VALU 0.85us -> compute-limited.
__global__ __launch_bounds__(256) void k_hbase(const float* __restrict__ hprev,
                                               const float* __restrict__ Wh,
                                               float* __restrict__ outp) {
  const int lane = threadIdx.x & 63;
  const int wid  = threadIdx.x >> 6;
  const int i  = blockIdx.x * 64 + lane;
  const int bb = blockIdx.y * 16 + wid * 4;
  const int k  = blockIdx.z;                    // eighth of the j-range
  const float4* wr = (const float4*)(Wh + (size_t)i * D_H + k * 128);
  const float4* h0 = (const float4*)(hprev + (size_t)(bb+0) * D_H + k * 128);
  const float4* h1 = (const float4*)(hprev + (size_t)(bb+1) * D_H + k * 128);
  const float4* h2 = (const float4*)(hprev + (size_t)(bb+2) * D_H + k * 128);
  const float4* h3 = (const float4*)(hprev + (size_t)(bb+3) * D_H + k * 128);
  float4 A0 = {0,0,0,0}, A1 = {0,0,0,0}, A2 = {0,0,0,0}, A3 = {0,0,0,0};
#pragma unroll 4
  for (int j = 0; j < 32; ++j) {                // 128 floats = eighth of D_H
    float4 w = wr[j];
    float4 x0 = h0[j], x1 = h1[j], x2 = h2[j], x3 = h3[j];
    FMA4(A0, x0) FMA4(A1, x1) FMA4(A2, x2) FMA4(A3, x3)
  }
  float* o = outp + (size_t)k * (BATCH * D_H);
  o[(size_t)(bb+0)*D_H + i] = (A0.x+A0.y)+(A0.z+A0.w);
  o[(size_t)(bb+1)*D_H + i] = (A1.x+A1.y)+(A1.z+A1.w);
  o[(size_t)(bb+2)*D_H + i] = (A2.x+A2.y)+(A2.z+A2.w);
  o[(size_t)(bb+3)*D_H + i] = (A3.x+A3.y)+(A3.z+A3.w);
}

// wave-wide sum; result valid in lane 0
__device__ inline float wred(float x) {
#pragma unroll
  for (int off = 32; off > 0; off >>= 1) x += __shfl_down(x, off);
  return x;
}

// gated refinement, timestep T (0..14). One WG per batch, 256 thr (4 waves),
// 4 elems/thread. Sync-minimized: 1 pre-reduce + 2 syncs per inner iter.
// LN stats of the gated update computed ANALYTICALLY:
//   sum(hn)  = oma*sum(hb) + ad*sum(ah)
//   sum(hn2) = oma^2*sum(hb2) + 2*oma*ad*sum(hb*ah) + ad^2*sum(ah2)
template<int T>
__global__ __launch_bounds__(256) void k_refine(
    const float* __restrict__ hbp, const float* __restrict__ zg,
    float* __restrict__ hist,
    const float* __restrict__ gamma, const float* __restrict__ beta,
    const float* __restrict__ alphap) {
  constexpr int TS = (T > 0) ? T : 1;
  __shared__ float lh[TS][D_H];          // history rows for this batch
  __shared__ float red[2][64];           // parity-alternated reduce scratch
  const int tid = threadIdx.x;
  const int b   = blockIdx.x;
  const int lane = tid & 63, w = tid >> 6;

  if constexpr (T > 0) {
    const float4* hist4 = (const float4*)hist;
    float4* lh4 = (float4*)lh;
#pragma unroll
    for (int s = 0; s < T; ++s)
      lh4[s * 256 + tid] = hist4[((size_t)s * BATCH + b) * 256 + tid];
  }

  float4 hb = ((const float4*)(zg + (size_t)b * D_H))[tid];
  if constexpr (T > 0) {                 // sum the 8 k-split Wh partials
    const float4* p = (const float4*)hbp;
    const size_t o = (size_t)b * 256 + tid;
#pragma unroll
    for (int k = 0; k < 8; ++k) {
      float4 pk = p[o + (size_t)k * 16384];
      hb.x += pk.x; hb.y += pk.y; hb.z += pk.z; hb.w += pk.w;
    }
  }
  const float4 gi = ((const float4*)gamma)[tid];
  const float4 bi = ((const float4*)beta)[tid];
  const float al = alphap[0];
  const float kk = (al >= 0.f) ? (1.f + log1pf(expf(al)))
                               : (1.f / (1.f + log1pf(expf(-al))));

  // pre-reduce (region 0): Shb, Shb2  (sync doubles as staging barrier)
  {
    float r0 = wred((hb.x + hb.y) + (hb.z + hb.w));
    float r1 = wred((hb.x*hb.x + hb.y*hb.y) + (hb.z*hb.z + hb.w*hb.w));
    if (lane == 0) { red[0][w] = r0; red[0][4 + w] = r1; }
  }
  __syncthreads();
  const float Shb  = (red[0][0] + red[0][1]) + (red[0][2] + red[0][3]);
  const float Shb2 = (red[0][4] + red[0][5]) + (red[0][6] + red[0][7]);
  float mu  = Shb * (1.f / D_H);
  float var = Shb2 * (1.f / D_H) - mu * mu;
  float rs  = rsqrtf(var + 1e-5f);
  float4 hc;
  hc.x = fmaxf(0.f, (hb.x - mu) * rs * gi.x + bi.x);
  hc.y = fmaxf(0.f, (hb.y - mu) * rs * gi.y + bi.y);
  hc.z = fmaxf(0.f, (hb.z - mu) * rs * gi.z + bi.z);
  hc.w = fmaxf(0.f, (hb.w - mu) * rs * gi.w + bi.w);

  if constexpr (T == 0) {
    // A == 0: Ah = 0 -> a_dyn = 0 -> h unchanged through all 3 iters
    ((float4*)(hist + (size_t)b * D_H))[tid] = hc;
    return;
  } else {
    const float4* lh4 = (const float4*)lh;
#pragma unroll 1
    for (int r = 0; r < 3; ++r) {
      // ---- d_s = h . h_s  (register partials -> region 1) ----
      float pd[T];
#pragma unroll
      for (int s = 0; s < T; ++s) {
        float4 lv = lh4[s * 256 + tid];
        pd[s] = (hc.x*lv.x + hc.y*lv.y) + (hc.z*lv.z + hc.w*lv.w);
      }
#pragma unroll
      for (int s = 0; s < T; ++s) {
        float t = wred(pd[s]);
        if (lane == 0) red[1][s * 4 + w] = t;
      }
      __syncthreads();
      float cf[T];
      {
        float lamc = ETAv;               // ETA * LAM^(T-1-s), s descending
#pragma unroll
        for (int s = T - 1; s >= 0; --s) {
          float ds = (red[1][s*4] + red[1][s*4+1])
                   + (red[1][s*4+2] + red[1][s*4+3]);
          cf[s] = lamc * ds;
          lamc *= LAMv;
        }
      }
      // ---- ah = sum_s cf[s] * h_s ----
      float4 ah = {0.f, 0.f, 0.f, 0.f};
#pragma unroll
      for (int s = 0; s < T; ++s) {
        float4 lv = lh4[s * 256 + tid];
        ah.x = fmaf(cf[s], lv.x, ah.x); ah.y = fmaf(cf[s], lv.y, ah.y);
        ah.z = fmaf(cf[s], lv.z, ah.z); ah.w = fmaf(cf[s], lv.w, ah.w);
      }
      // ---- single 5-value reduction (region 0) ----
      {
        float q0 = wred((hc.x*ah.x + hc.y*ah.y) + (hc.z*ah.z + hc.w*ah.w));
        float q1 = wred((hc.x*hc.x + hc.y*hc.y) + (hc.z*hc.z + hc.w*hc.w));
        float q2 = wred((ah.x*ah.x + ah.y*ah.y) + (ah.z*ah.z + ah.w*ah.w));
        float q3 = wred((hb.x*ah.x + hb.y*ah.y) + (hb.z*ah.z + hb.w*ah.w));
        float q4 = wred((ah.x + ah.y) + (ah.z + ah.w));
        if (lane == 0) {
          red[0][w] = q0; red[0][4+w] = q1; red[0][8+w] = q2;
          red[0][12+w] = q3; red[0][16+w] = q4;
        }
      }
      __syncthreads();
      float S_hAh  = (red[0][0]+red[0][1])+(red[0][2]+red[0][3]);
      float S_h2   = (red[0][4]+red[0][5])+(red[0][6]+red[0][7]);
      float S_Ah2  = (red[0][8]+red[0][9])+(red[0][10]+red[0][11]);
      float S_hbAh = (red[0][12]+red[0][13])+(red[0][14]+red[0][15]);
      float S_ah   = (red[0][16]+red[0][17])+(red[0][18]+red[0][19]);
      float n1 = sqrtf(S_h2) + 1e-6f;
      float n2 = sqrtf(S_Ah2) + 1e-6f;
      float R  = S_hAh / (n1 * n2 + 1e-6f);
      float Rp = fminf(fmaxf(R, 0.f), 1.f);
      float ad = 1.f - powf(1.f - Rp, kk);
      float oma = 1.f - ad * ad;
      float4 hn;
      hn.x = oma*hb.x + ad*ah.x; hn.y = oma*hb.y + ad*ah.y;
      hn.z = oma*hb.z + ad*ah.z; hn.w = oma*hb.w + ad*ah.w;
      float Shn  = oma * Shb + ad * S_ah;
      float Shn2 = oma*oma*Shb2 + 2.f*oma*ad*S_hbAh + ad*ad*S_Ah2;
      float mu2  = Shn * (1.f / D_H);
      float var2 = Shn2 * (1.f / D_H) - mu2 * mu2;
      float rs2  = rsqrtf(var2 + 1e-5f);
      hc.x = fmaxf(0.f, (hn.x - mu2) * rs2 * gi.x + bi.x);
      hc.y = fmaxf(0.f, (hn.y - mu2) * rs2 * gi.y + bi.y);
      hc.z = fmaxf(0.f, (hn.z - mu2) * rs2 * gi.z + bi.z);
      hc.w = fmaxf(0.f, (hn.w - mu2) * rs2 * gi.w + bi.w);
    }
    ((float4*)(hist + ((size_t)T * BATCH + b) * D_H))[tid] = hc;
  }
}

// final timestep: h = relu(LN(h_base + A@h)) x3, A = A_14 (rank 15).
// All 15 rows in LDS (60 KB + scratch).  hn = hb + ah ->
// Shn = Shb + Sah; Shn2 = Shb2 + 2*S_hbAh + S_Ah2.
__global__ __launch_bounds__(256) void k_refine_final(
    const float* __restrict__ hbp, const float* __restrict__ zg,
    const float* __restrict__ hist, float* __restrict__ hfin,
    const float* __restrict__ gamma, const float* __restrict__ beta) {
  __shared__ float lh[15][D_H];
  __shared__ float red[2][64];
  const int tid = threadIdx.x;
  const int b   = blockIdx.x;
  const int lane = tid & 63, w = tid >> 6;
  {
    const float4* hist4 = (const float4*)hist;
    float4* lh4 = (float4*)lh;
#pragma unroll
    for (int s = 0; s < 15; ++s)
      lh4[s * 256 + tid] = hist4[((size_t)s * BATCH + b) * 256 + tid];
  }
  float4 hb = ((const float4*)(zg + (size_t)b * D_H))[tid];
  {
    const float4* p = (const float4*)hbp;
    const size_t o = (size_t)b * 256 + tid;
#pragma unroll
    for (int k = 0; k < 8; ++k) {
      float4 pk = p[o + (size_t)k * 16384];
      hb.x += pk.x; hb.y += pk.y; hb.z += pk.z; hb.w += pk.w;
    }
  }
  const float4 gi = ((const float4*)gamma)[tid];
  const float4 bi = ((const float4*)beta)[tid];

  {
    float r0 = wred((hb.x + hb.y) + (hb.z + hb.w));
    float r1 = wred((hb.x*hb.x + hb.y*hb.y) + (hb.z*hb.z + hb.w*hb.w));
    if (lane == 0) { red[0][w] = r0; red[0][4 + w] = r1; }
  }
  __syncthreads();
  const float Shb  = (red[0][0] + red[0][1]) + (red[0][2] + red[0][3]);
  const float Shb2 = (red[0][4] + red[0][5]) + (red[0][6] + red[0][7]);
  float mu  = Shb * (1.f / D_H);
  float var = Shb2 * (1.f / D_H) - mu * mu;
  float rs  = rsqrtf(var + 1e-5f);
  float4 hc;
  hc.x = fmaxf(0.f, (hb.x - mu) * rs * gi.x + bi.x);
  hc.y = fmaxf(0.f, (hb.y - mu) * rs * gi.y + bi.y);
  hc.z = fmaxf(0.f, (hb.z - mu) * rs * gi.z + bi.z);
  hc.w = fmaxf(0.f, (hb.w - mu) * rs * gi.w + bi.w);

  const float4* lh4 = (const float4*)lh;
#pragma unroll 1
  for (int r = 0; r < 3; ++r) {
    float pd[15];
#pragma unroll
    for (int s = 0; s < 15; ++s) {
      float4 lv = lh4[s * 256 + tid];
      pd[s] = (hc.x*lv.x + hc.y*lv.y) + (hc.z*lv.z + hc.w*lv.w);
    }
#pragma unroll
    for (int s = 0; s < 15; ++s) {
      float t = wred(pd[s]);
      if (lane == 0) red[1][s * 4 + w] = t;
    }
    __syncthreads();
    float cf[15];
    {
      float lamc = ETAv;                 // ETA * LAM^(14-s), s descending
#pragma unroll
      for (int s = 14; s >= 0; --s) {
        float ds = (red[1][s*4] + red[1][s*4+1])
                 + (red[1][s*4+2] + red[1][s*4+3]);
        cf[s] = lamc * ds;
        lamc *= LAMv;
      }
    }
    float4 ah = {0.f, 0.f, 0.f, 0.f};
#pragma unroll
    for (int s = 0; s < 15; ++s) {
      float4 lv = lh4[s * 256 + tid];
      ah.x = fmaf(cf[s], lv.x, ah.x); ah.y = fmaf(cf[s], lv.y, ah.y);
      ah.z = fmaf(cf[s], lv.z, ah.z); ah.w = fmaf(cf[s], lv.w, ah.w);
    }
    {
      float q0 = wred((hb.x*ah.x + hb.y*ah.y) + (hb.z*ah.z + hb.w*ah.w));
      float q1 = wred((ah.x*ah.x + ah.y*ah.y) + (ah.z*ah.z + ah.w*ah.w));
      float q2 = wred((ah.x + ah.y) + (ah.z + ah.w));
      if (lane == 0) { red[0][w] = q0; red[0][4+w] = q1; red[0][8+w] = q2; }
    }
    __syncthreads();
    float S_hbAh = (red[0][0]+red[0][1])+(red[0][2]+red[0][3]);
    float S_Ah2  = (red[0][4]+red[0][5])+(red[0][6]+red[0][7]);
    float S_ah   = (red[0][8]+red[0][9])+(red[0][10]+red[0][11]);
    float4 hn;
    hn.x = hb.x + ah.x; hn.y = hb.y + ah.y;
    hn.z = hb.z + ah.z; hn.w = hb.w + ah.w;
    float Shn  = Shb + S_ah;
    float Shn2 = Shb2 + 2.f * S_hbAh + S_Ah2;
    float mu2  = Shn * (1.f / D_H);
    float var2 = Shn2 * (1.f / D_H) - mu2 * mu2;
    float rs2  = rsqrtf(var2 + 1e-5f);
    hc.x = fmaxf(0.f, (hn.x - mu2) * rs2 * gi.x + bi.x);
    hc.y = fmaxf(0.f, (hn.y - mu2) * rs2 * gi.y + bi.y);
    hc.z = fmaxf(0.f, (hn.z - mu2) * rs2 * gi.z + bi.z);
    hc.w = fmaxf(0.f, (hn.w - mu2) * rs2 * gi.w + bi.w);
  }
  ((float4*)(hfin + (size_t)b * D_H))[tid] = hc;
}

// Partial head: predp[k][b][o] = sum_{j in k-th quarter} hW[o][j] hfin[b][j]
// grid (8 o, 8 by, 4 k) = 256 blocks (full machine), 2 batches/thread.
// Bias + partial sum folded into k_loss_final.
__global__ __launch_bounds__(256) void k_head(const float* __restrict__ hfin,
                                              const float* __restrict__ hW,
                                              float* __restrict__ predp) {
  const int lane = threadIdx.x & 63;
  const int wid  = threadIdx.x >> 6;
  const int o  = blockIdx.x * 64 + lane;
  const int b0 = blockIdx.y * 8 + wid;
  const int b1 = b0 + 4;
  const int k  = blockIdx.z;                    // quarter of the j-range
  const float4* wr  = (const float4*)(hW + (size_t)o * D_H + k * 256);
  const float4* h0r = (const float4*)(hfin + (size_t)b0 * D_H + k * 256);
  const float4* h1r = (const float4*)(hfin + (size_t)b1 * D_H + k * 256);
  float4 A0 = {0,0,0,0}, A1 = {0,0,0,0};
#pragma unroll 4
  for (int j = 0; j < 64; ++j) {                // 256 floats = quarter of D_H
    float4 w = wr[j];
    float4 x0 = h0r[j], x1 = h1r[j];
    FMA4(A0, x0) FMA4(A1, x1)
  }
  float* op = predp + (size_t)k * (BATCH * D_OUT);
  op[(size_t)b0*D_OUT + o] = (A0.x+A0.y)+(A0.z+A0.w);
  op[(size_t)b1*D_OUT + o] = (A1.x+A1.y)+(A1.z+A1.w);
}

// fused: assemble pred (4 partials + bias), per-batch loss terms, final mean.
// One block, 1024 threads; wave w handles batches w*4..w*4+3.
__global__ __launch_bounds__(1024) void k_loss_final(
    const float* __restrict__ predp, const float* __restrict__ hbias,
    const float* __restrict__ clean, float* __restrict__ out) {
  __shared__ float bl[64], ba[64];
  const int tid = threadIdx.x;
  const int w = tid >> 6, lane = tid & 63;
#pragma unroll
  for (int q = 0; q < 4; ++q) {
    const int b = w * 4 + q;
    float sd=0, sc=0, spc=0, sp=0;
#pragma unroll
    for (int e = 0; e < 8; ++e) {
      int o = e * 64 + lane;
      size_t idx = (size_t)b * D_OUT + o;
      float p = predp[idx] + predp[idx + 32768] + predp[idx + 2*32768]
              + predp[idx + 3*32768] + hbias[o];
      float c = clean[idx];
      float d = p - c;
      sd = fmaf(d,d,sd); sc = fmaf(c,c,sc);
      spc = fmaf(p,c,spc); sp = fmaf(p,p,sp);
    }
#pragma unroll
    for (int off = 32; off > 0; off >>= 1) {
      sd += __shfl_down(sd, off); sc += __shfl_down(sc, off);
      spc += __shfl_down(spc, off); sp += __shfl_down(sp, off);
    }
    if (lane == 0) {
      bl[b] = sd / (sc + 1e-6f);
      ba[b] = spc / ((sqrtf(sp) + 1e-6f) * (sqrtf(sc) + 1e-6f));
    }
  }
  __syncthreads();
  if (w == 0) {
    float l = bl[lane], a = ba[lane];
#pragma unroll
    for (int off = 32; off > 0; off >>= 1) {
      l += __shfl_down(l, off); a += __shfl_down(a, off);
    }
    if (lane == 0) {
      out[0] = l * (1.f / BATCH);
      out[1] = a * (1.f / BATCH);
    }
  }
}

extern "C" void kernel_launch(void* const* d_in, const int* in_sizes, int n_in,
                              void* d_out, int out_size, void* d_ws, size_t ws_size,
                              hipStream_t stream) {
  (void)in_sizes; (void)n_in; (void)out_size; (void)ws_size;
  const float* z     = (const float*)d_in[0];   // [16][64][512]
  const float* clean = (const float*)d_in[1];   // [64][512]
  const float* Wh    = (const float*)d_in[2];   // [1024][1024]
  const float* Wg    = (const float*)d_in[3];   // [1024][512]
  const float* bh    = (const float*)d_in[4];   // [1024]
  const float* gam   = (const float*)d_in[5];   // [1024]
  const float* bet   = (const float*)d_in[6];   // [1024]
  const float* alp   = (const float*)d_in[7];   // [1]
  const float* hW    = (const float*)d_in[8];   // [512][1024]
  const float* hbias = (const float*)d_in[9];   // [512]

  float* ws    = (float*)d_ws;
  float* hist  = ws;                          // 15*65536
  float* hbp   = hist + 15 * 65536;           // 8*65536 (k-split partials)
  float* zg    = hbp + 8 * 65536;             // 16*65536 (hoisted z@Wg^T + b)
  float* hfin  = zg + 16 * 65536;             // 65536
  float* predp = hfin + 65536;                // 4*32768

  // all 16 z@Wg^T + bias, one fully-parallel launch (input-only)
  k_zg<<<dim3(16, 4, 16), dim3(256), 0, stream>>>(z, Wg, bh, zg);

#define REFINE_CASE(T) case T: \
    k_refine<T><<<dim3(64), dim3(256), 0, stream>>>( \
        hbp, zg + (size_t)T * 65536, hist, gam, bet, alp); break;

  // t = 0: h_prev == 0 -> h_base == zg[0]; no hbase launch at all
  k_refine<0><<<dim3(64), dim3(256), 0, stream>>>(hbp, zg, hist, gam, bet, alp);

  for (int t = 1; t < 15; ++t) {
    k_hbase<<<dim3(16, 4, 8), dim3(256), 0, stream>>>(
        hist + (size_t)(t - 1) * 65536, Wh, hbp);
    switch (t) {
      REFINE_CASE(1)  REFINE_CASE(2)  REFINE_CASE(3)  REFINE_CASE(4)
      REFINE_CASE(5)  REFINE_CASE(6)  REFINE_CASE(7)  REFINE_CASE(8)
      REFINE_CASE(9)  REFINE_CASE(10) REFINE_CASE(11) REFINE_CASE(12)
      REFINE_CASE(13) REFINE_CASE(14)
    }
  }
#undef REFINE_CASE

  k_hbase<<<dim3(16, 4, 8), dim3(256), 0, stream>>>(
      hist + (size_t)14 * 65536, Wh, hbp);
  k_refine_final<<<dim3(64), dim3(256), 0, stream>>>(
      hbp, zg + (size_t)15 * 65536, hist, hfin, gam, bet);
  k_head<<<dim3(8, 8, 4), dim3(256), 0, stream>>>(hfin, hW, predp);
  k_loss_final<<<dim3(1), dim3(1024), 0, stream>>>(
      predp, hbias, clean, (float*)d_out);
}

// Round 8
// 482.711 us; speedup vs baseline: 1.4300x; 1.4300x over previous
//
#include <hip/hip_runtime.h>

#define D_G   512
#define D_H   1024
#define D_OUT 512
#define BATCH 64
#define LAMv  0.95f
#define ETAv  0.5f

// ---------------------------------------------------------------------------
// ws layout (floats):
//   hist : 15 * 65536    hbp : 16 * 65536    zg : 16 * 65536
//   hfin : 65536         predp: 16 * 32768
//   WhT  : 1024*1024     WgT : 512*1024      hWT: 1024*512
// total ~22 MiB
// ---------------------------------------------------------------------------

__device__ inline float4 f4fma(float4 w, float s, float4 a) {
  a.x = fmaf(w.x, s, a.x); a.y = fmaf(w.y, s, a.y);
  a.z = fmaf(w.z, s, a.z); a.w = fmaf(w.w, s, a.w);
  return a;
}

// dst[c][r] = src[r][c]; src is R x C. grid (C/64, R/64), 256 thr.
__global__ __launch_bounds__(256) void k_tr(const float* __restrict__ src,
                                            float* __restrict__ dst,
                                            int R, int C) {
  __shared__ float t[64][65];
  const int c0 = blockIdx.x * 64, r0 = blockIdx.y * 64;
  const int tid = threadIdx.x;
  const int lr = tid >> 4;            // 0..15
  const int lc = (tid & 15) * 4;      // 0,4,..,60
#pragma unroll
  for (int p = 0; p < 4; ++p) {
    int r = lr + p * 16;
    float4 v = *(const float4*)&src[(size_t)(r0 + r) * C + c0 + lc];
    t[r][lc] = v.x; t[r][lc+1] = v.y; t[r][lc+2] = v.z; t[r][lc+3] = v.w;
  }
  __syncthreads();
#pragma unroll
  for (int p = 0; p < 4; ++p) {
    int c = lr + p * 16;
    float4 v = make_float4(t[lc][c], t[lc+1][c], t[lc+2][c], t[lc+3][c]);
    *(float4*)&dst[(size_t)(c0 + c) * R + r0 + lc] = v;
  }
}

// zg[t][b][i] = z[t][b][:].Wg[i][:] + bh[i], via WgT (coalesced weights).
// grid (4 iq, 8 by, 16 t), 256 thr. Thread: 4 consecutive i, 2 batches.
// Weight float4 loads: 64 lanes x 16B contiguous. Activations: wave-uniform
// broadcast streams.
__global__ __launch_bounds__(256) void k_zg(const float* __restrict__ z,
                                            const float* __restrict__ WgT,
                                            const float* __restrict__ bh,
                                            float* __restrict__ zg) {
  const int lane = threadIdx.x & 63;
  const int wid  = __builtin_amdgcn_readfirstlane(threadIdx.x >> 6);
  const int iq   = blockIdx.x * 64 + lane;      // i-quad index; i0 = 4*iq
  const int b0   = blockIdx.y * 8 + wid * 2;
  const int t    = blockIdx.z;
  const float4* w4  = (const float4*)WgT;       // [j][i]: idx jq*1024 + iq
  const float4* zr0 = (const float4*)(z + ((size_t)t * BATCH + b0) * D_G);
  const float4* zr1 = (const float4*)(z + ((size_t)t * BATCH + b0 + 1) * D_G);
  float4 A0 = {0,0,0,0}, A1 = {0,0,0,0};
#pragma unroll 2
  for (int jq = 0; jq < D_G / 4; ++jq) {
    float4 zv0 = zr0[jq], zv1 = zr1[jq];
    float4 wa = w4[(size_t)jq*1024 +       iq];
    float4 wb = w4[(size_t)jq*1024 + 256 + iq];
    float4 wc = w4[(size_t)jq*1024 + 512 + iq];
    float4 wd = w4[(size_t)jq*1024 + 768 + iq];
    A0 = f4fma(wa, zv0.x, A0); A0 = f4fma(wb, zv0.y, A0);
    A0 = f4fma(wc, zv0.z, A0); A0 = f4fma(wd, zv0.w, A0);
    A1 = f4fma(wa, zv1.x, A1); A1 = f4fma(wb, zv1.y, A1);
    A1 = f4fma(wc, zv1.z, A1); A1 = f4fma(wd, zv1.w, A1);
  }
  float4 bias = ((const float4*)bh)[iq];
  A0.x += bias.x; A0.y += bias.y; A0.z += bias.z; A0.w += bias.w;
  A1.x += bias.x; A1.y += bias.y; A1.z += bias.z; A1.w += bias.w;
  float4* o = (float4*)(zg + (size_t)t * (BATCH * D_H));
  o[(size_t)b0 * 256 + iq] = A0;
  o[(size_t)(b0 + 1) * 256 + iq] = A1;
}

// Partial h@Wh^T via WhT. grid (4 iq, 8 by, 16 k) = 512 blocks (2 waves/SIMD).
// outp[k][b][i] = sum_{j in k-th 1/16} WhT[j][i] * hprev[b][j]
__global__ __launch_bounds__(256) void k_hbase(const float* __restrict__ hprev,
                                               const float* __restrict__ WhT,
                                               float* __restrict__ outp) {
  const int lane = threadIdx.x & 63;
  const int wid  = __builtin_amdgcn_readfirstlane(threadIdx.x >> 6);
  const int iq   = blockIdx.x * 64 + lane;
  const int b0   = blockIdx.y * 8 + wid * 2;
  const int k    = blockIdx.z;                  // 1/16 of j-range (64 j)
  const float4* w4  = (const float4*)WhT;
  const float4* h0  = (const float4*)(hprev + (size_t)b0 * D_H);
  const float4* h1  = (const float4*)(hprev + (size_t)(b0 + 1) * D_H);
  float4 A0 = {0,0,0,0}, A1 = {0,0,0,0};
  const int jq0 = k * 16;
#pragma unroll 2
  for (int jq = jq0; jq < jq0 + 16; ++jq) {
    float4 hv0 = h0[jq], hv1 = h1[jq];
    float4 wa = w4[(size_t)jq*1024 +       iq];
    float4 wb = w4[(size_t)jq*1024 + 256 + iq];
    float4 wc = w4[(size_t)jq*1024 + 512 + iq];
    float4 wd = w4[(size_t)jq*1024 + 768 + iq];
    A0 = f4fma(wa, hv0.x, A0); A0 = f4fma(wb, hv0.y, A0);
    A0 = f4fma(wc, hv0.z, A0); A0 = f4fma(wd, hv0.w, A0);
    A1 = f4fma(wa, hv1.x, A1); A1 = f4fma(wb, hv1.y, A1);
    A1 = f4fma(wc, hv1.z, A1); A1 = f4fma(wd, hv1.w, A1);
  }
  float4* o = (float4*)(outp + (size_t)k * (BATCH * D_H));
  o[(size_t)b0 * 256 + iq] = A0;
  o[(size_t)(b0 + 1) * 256 + iq] = A1;
}

// wave-wide sum; result valid in lane 0
__device__ inline float wred(float x) {
#pragma unroll
  for (int off = 32; off > 0; off >>= 1) x += __shfl_down(x, off);
  return x;
}

// gated refinement, timestep T (0..14). One WG per batch, 256 thr (4 waves),
// 4 elems/thread. LN stats of the gated update computed analytically.
template<int T>
__global__ __launch_bounds__(256) void k_refine(
    const float* __restrict__ hbp, const float* __restrict__ zg,
    float* __restrict__ hist,
    const float* __restrict__ gamma, const float* __restrict__ beta,
    const float* __restrict__ alphap) {
  constexpr int TS = (T > 0) ? T : 1;
  __shared__ float lh[TS][D_H];          // history rows for this batch
  __shared__ float red[2][64];           // parity-alternated reduce scratch
  const int tid = threadIdx.x;
  const int b   = blockIdx.x;
  const int lane = tid & 63, w = tid >> 6;

  if constexpr (T > 0) {
    const float4* hist4 = (const float4*)hist;
    float4* lh4 = (float4*)lh;
#pragma unroll
    for (int s = 0; s < T; ++s)
      lh4[s * 256 + tid] = hist4[((size_t)s * BATCH + b) * 256 + tid];
  }

  float4 hb = ((const float4*)(zg + (size_t)b * D_H))[tid];
  if constexpr (T > 0) {                 // sum the 16 k-split Wh partials
    const float4* p = (const float4*)hbp;
    const size_t o = (size_t)b * 256 + tid;
#pragma unroll
    for (int k = 0; k < 16; ++k) {
      float4 pk = p[o + (size_t)k * 16384];
      hb.x += pk.x; hb.y += pk.y; hb.z += pk.z; hb.w += pk.w;
    }
  }
  const float4 gi = ((const float4*)gamma)[tid];
  const float4 bi = ((const float4*)beta)[tid];
  const float al = alphap[0];
  const float kk = (al >= 0.f) ? (1.f + log1pf(expf(al)))
                               : (1.f / (1.f + log1pf(expf(-al))));

  // pre-reduce (region 0): Shb, Shb2  (sync doubles as staging barrier)
  {
    float r0 = wred((hb.x + hb.y) + (hb.z + hb.w));
    float r1 = wred((hb.x*hb.x + hb.y*hb.y) + (hb.z*hb.z + hb.w*hb.w));
    if (lane == 0) { red[0][w] = r0; red[0][4 + w] = r1; }
  }
  __syncthreads();
  const float Shb  = (red[0][0] + red[0][1]) + (red[0][2] + red[0][3]);
  const float Shb2 = (red[0][4] + red[0][5]) + (red[0][6] + red[0][7]);
  float mu  = Shb * (1.f / D_H);
  float var = Shb2 * (1.f / D_H) - mu * mu;
  float rs  = rsqrtf(var + 1e-5f);
  float4 hc;
  hc.x = fmaxf(0.f, (hb.x - mu) * rs * gi.x + bi.x);
  hc.y = fmaxf(0.f, (hb.y - mu) * rs * gi.y + bi.y);
  hc.z = fmaxf(0.f, (hb.z - mu) * rs * gi.z + bi.z);
  hc.w = fmaxf(0.f, (hb.w - mu) * rs * gi.w + bi.w);

  if constexpr (T == 0) {
    // A == 0: Ah = 0 -> a_dyn = 0 -> h unchanged through all 3 iters
    ((float4*)(hist + (size_t)b * D_H))[tid] = hc;
    return;
  } else {
    const float4* lh4 = (const float4*)lh;
#pragma unroll 1
    for (int r = 0; r < 3; ++r) {
      // ---- d_s = h . h_s  (register partials -> region 1) ----
      float pd[T];
#pragma unroll
      for (int s = 0; s < T; ++s) {
        float4 lv = lh4[s * 256 + tid];
        pd[s] = (hc.x*lv.x + hc.y*lv.y) + (hc.z*lv.z + hc.w*lv.w);
      }
#pragma unroll
      for (int s = 0; s < T; ++s) {
        float t = wred(pd[s]);
        if (lane == 0) red[1][s * 4 + w] = t;
      }
      __syncthreads();
      float cf[T];
      {
        float lamc = ETAv;               // ETA * LAM^(T-1-s), s descending
#pragma unroll
        for (int s = T - 1; s >= 0; --s) {
          float ds = (red[1][s*4] + red[1][s*4+1])
                   + (red[1][s*4+2] + red[1][s*4+3]);
          cf[s] = lamc * ds;
          lamc *= LAMv;
        }
      }
      // ---- ah = sum_s cf[s] * h_s ----
      float4 ah = {0.f, 0.f, 0.f, 0.f};
#pragma unroll
      for (int s = 0; s < T; ++s) {
        float4 lv = lh4[s * 256 + tid];
        ah.x = fmaf(cf[s], lv.x, ah.x); ah.y = fmaf(cf[s], lv.y, ah.y);
        ah.z = fmaf(cf[s], lv.z, ah.z); ah.w = fmaf(cf[s], lv.w, ah.w);
      }
      // ---- single 5-value reduction (region 0) ----
      {
        float q0 = wred((hc.x*ah.x + hc.y*ah.y) + (hc.z*ah.z + hc.w*ah.w));
        float q1 = wred((hc.x*hc.x + hc.y*hc.y) + (hc.z*hc.z + hc.w*hc.w));
        float q2 = wred((ah.x*ah.x + ah.y*ah.y) + (ah.z*ah.z + ah.w*ah.w));
        float q3 = wred((hb.x*ah.x + hb.y*ah.y) + (hb.z*ah.z + hb.w*ah.w));
        float q4 = wred((ah.x + ah.y) + (ah.z + ah.w));
        if (lane == 0) {
          red[0][w] = q0; red[0][4+w] = q1; red[0][8+w] = q2;
          red[0][12+w] = q3; red[0][16+w] = q4;
        }
      }
      __syncthreads();
      float S_hAh  = (red[0][0]+red[0][1])+(red[0][2]+red[0][3]);
      float S_h2   = (red[0][4]+red[0][5])+(red[0][6]+red[0][7]);
      float S_Ah2  = (red[0][8]+red[0][9])+(red[0][10]+red[0][11]);
      float S_hbAh = (red[0][12]+red[0][13])+(red[0][14]+red[0][15]);
      float S_ah   = (red[0][16]+red[0][17])+(red[0][18]+red[0][19]);
      float n1 = sqrtf(S_h2) + 1e-6f;
      float n2 = sqrtf(S_Ah2) + 1e-6f;
      float R  = S_hAh / (n1 * n2 + 1e-6f);
      float Rp = fminf(fmaxf(R, 0.f), 1.f);
      float ad = 1.f - powf(1.f - Rp, kk);
      float oma = 1.f - ad * ad;
      float4 hn;
      hn.x = oma*hb.x + ad*ah.x; hn.y = oma*hb.y + ad*ah.y;
      hn.z = oma*hb.z + ad*ah.z; hn.w = oma*hb.w + ad*ah.w;
      float Shn  = oma * Shb + ad * S_ah;
      float Shn2 = oma*oma*Shb2 + 2.f*oma*ad*S_hbAh + ad*ad*S_Ah2;
      float mu2  = Shn * (1.f / D_H);
      float var2 = Shn2 * (1.f / D_H) - mu2 * mu2;
      float rs2  = rsqrtf(var2 + 1e-5f);
      hc.x = fmaxf(0.f, (hn.x - mu2) * rs2 * gi.x + bi.x);
      hc.y = fmaxf(0.f, (hn.y - mu2) * rs2 * gi.y + bi.y);
      hc.z = fmaxf(0.f, (hn.z - mu2) * rs2 * gi.z + bi.z);
      hc.w = fmaxf(0.f, (hn.w - mu2) * rs2 * gi.w + bi.w);
    }
    ((float4*)(hist + ((size_t)T * BATCH + b) * D_H))[tid] = hc;
  }
}

// final timestep: h = relu(LN(h_base + A@h)) x3, A = A_14 (rank 15).
__global__ __launch_bounds__(256) void k_refine_final(
    const float* __restrict__ hbp, const float* __restrict__ zg,
    const float* __restrict__ hist, float* __restrict__ hfin,
    const float* __restrict__ gamma, const float* __restrict__ beta) {
  __shared__ float lh[15][D_H];
  __shared__ float red[2][64];
  const int tid = threadIdx.x;
  const int b   = blockIdx.x;
  const int lane = tid & 63, w = tid >> 6;
  {
    const float4* hist4 = (const float4*)hist;
    float4* lh4 = (float4*)lh;
#pragma unroll
    for (int s = 0; s < 15; ++s)
      lh4[s * 256 + tid] = hist4[((size_t)s * BATCH + b) * 256 + tid];
  }
  float4 hb = ((const float4*)(zg + (size_t)b * D_H))[tid];
  {
    const float4* p = (const float4*)hbp;
    const size_t o = (size_t)b * 256 + tid;
#pragma unroll
    for (int k = 0; k < 16; ++k) {
      float4 pk = p[o + (size_t)k * 16384];
      hb.x += pk.x; hb.y += pk.y; hb.z += pk.z; hb.w += pk.w;
    }
  }
  const float4 gi = ((const float4*)gamma)[tid];
  const float4 bi = ((const float4*)beta)[tid];

  {
    float r0 = wred((hb.x + hb.y) + (hb.z + hb.w));
    float r1 = wred((hb.x*hb.x + hb.y*hb.y) + (hb.z*hb.z + hb.w*hb.w));
    if (lane == 0) { red[0][w] = r0; red[0][4 + w] = r1; }
  }
  __syncthreads();
  const float Shb  = (red[0][0] + red[0][1]) + (red[0][2] + red[0][3]);
  const float Shb2 = (red[0][4] + red[0][5]) + (red[0][6] + red[0][7]);
  float mu  = Shb * (1.f / D_H);
  float var = Shb2 * (1.f / D_H) - mu * mu;
  float rs  = rsqrtf(var + 1e-5f);
  float4 hc;
  hc.x = fmaxf(0.f, (hb.x - mu) * rs * gi.x + bi.x);
  hc.y = fmaxf(0.f, (hb.y - mu) * rs * gi.y + bi.y);
  hc.z = fmaxf(0.f, (hb.z - mu) * rs * gi.z + bi.z);
  hc.w = fmaxf(0.f, (hb.w - mu) * rs * gi.w + bi.w);

  const float4* lh4 = (const float4*)lh;
#pragma unroll 1
  for (int r = 0; r < 3; ++r) {
    float pd[15];
#pragma unroll
    for (int s = 0; s < 15; ++s) {
      float4 lv = lh4[s * 256 + tid];
      pd[s] = (hc.x*lv.x + hc.y*lv.y) + (hc.z*lv.z + hc.w*lv.w);
    }
#pragma unroll
    for (int s = 0; s < 15; ++s) {
      float t = wred(pd[s]);
      if (lane == 0) red[1][s * 4 + w] = t;
    }
    __syncthreads();
    float cf[15];
    {
      float lamc = ETAv;                 // ETA * LAM^(14-s), s descending
#pragma unroll
      for (int s = 14; s >= 0; --s) {
        float ds = (red[1][s*4] + red[1][s*4+1])
                 + (red[1][s*4+2] + red[1][s*4+3]);
        cf[s] = lamc * ds;
        lamc *= LAMv;
      }
    }
    float4 ah = {0.f, 0.f, 0.f, 0.f};
#pragma unroll
    for (int s = 0; s < 15; ++s) {
      float4 lv = lh4[s * 256 + tid];
      ah.x = fmaf(cf[s], lv.x, ah.x); ah.y = fmaf(cf[s], lv.y, ah.y);
      ah.z = fmaf(cf[s], lv.z, ah.z); ah.w = fmaf(cf[s], lv.w, ah.w);
    }
    {
      float q0 = wred((hb.x*ah.x + hb.y*ah.y) + (hb.z*ah.z + hb.w*ah.w));
      float q1 = wred((ah.x*ah.x + ah.y*ah.y) + (ah.z*ah.z + ah.w*ah.w));
      float q2 = wred((ah.x + ah.y) + (ah.z + ah.w));
      if (lane == 0) { red[0][w] = q0; red[0][4+w] = q1; red[0][8+w] = q2; }
    }
    __syncthreads();
    float S_hbAh = (red[0][0]+red[0][1])+(red[0][2]+red[0][3]);
    float S_Ah2  = (red[0][4]+red[0][5])+(red[0][6]+red[0][7]);
    float S_ah   = (red[0][8]+red[0][9])+(red[0][10]+red[0][11]);
    float4 hn;
    hn.x = hb.x + ah.x; hn.y = hb.y + ah.y;
    hn.z = hb.z + ah.z; hn.w = hb.w + ah.w;
    float Shn  = Shb + S_ah;
    float Shn2 = Shb2 + 2.f * S_hbAh + S_Ah2;
    float mu2  = Shn * (1.f / D_H);
    float var2 = Shn2 * (1.f / D_H) - mu2 * mu2;
    float rs2  = rsqrtf(var2 + 1e-5f);
    hc.x = fmaxf(0.f, (hn.x - mu2) * rs2 * gi.x + bi.x);
    hc.y = fmaxf(0.f, (hn.y - mu2) * rs2 * gi.y + bi.y);
    hc.z = fmaxf(0.f, (hn.z - mu2) * rs2 * gi.z + bi.z);
    hc.w = fmaxf(0.f, (hn.w - mu2) * rs2 * gi.w + bi.w);
  }
  ((float4*)(hfin + (size_t)b * D_H))[tid] = hc;
}

// Partial head via hWT [1024 j][512 o]. grid (2 oq, 8 by, 16 k), 256 thr.
// predp[k][b][o] = sum_{j in k-th 1/16} hWT[j][o] * hfin[b][j]
__global__ __launch_bounds__(256) void k_head(const float* __restrict__ hfin,
                                              const float* __restrict__ hWT,
                                              float* __restrict__ predp) {
  const int lane = threadIdx.x & 63;
  const int wid  = __builtin_amdgcn_readfirstlane(threadIdx.x >> 6);
  const int oq   = blockIdx.x * 64 + lane;      // o-quad; o0 = 4*oq
  const int b0   = blockIdx.y * 8 + wid * 2;
  const int k    = blockIdx.z;
  const float4* w4 = (const float4*)hWT;        // idx jq*512 + oq
  const float4* h0 = (const float4*)(hfin + (size_t)b0 * D_H);
  const float4* h1 = (const float4*)(hfin + (size_t)(b0 + 1) * D_H);
  float4 A0 = {0,0,0,0}, A1 = {0,0,0,0};
  const int jq0 = k * 16;
#pragma unroll 2
  for (int jq = jq0; jq < jq0 + 16; ++jq) {
    float4 hv0 = h0[jq], hv1 = h1[jq];
    float4 wa = w4[(size_t)jq*512 +       oq];
    float4 wb = w4[(size_t)jq*512 + 128 + oq];
    float4 wc = w4[(size_t)jq*512 + 256 + oq];
    float4 wd = w4[(size_t)jq*512 + 384 + oq];
    A0 = f4fma(wa, hv0.x, A0); A0 = f4fma(wb, hv0.y, A0);
    A0 = f4fma(wc, hv0.z, A0); A0 = f4fma(wd, hv0.w, A0);
    A1 = f4fma(wa, hv1.x, A1); A1 = f4fma(wb, hv1.y, A1);
    A1 = f4fma(wc, hv1.z, A1); A1 = f4fma(wd, hv1.w, A1);
  }
  float4* o = (float4*)(predp + (size_t)k * (BATCH * D_OUT));
  o[(size_t)b0 * 128 + oq] = A0;
  o[(size_t)(b0 + 1) * 128 + oq] = A1;
}

// fused: assemble pred (16 partials + bias), per-batch loss, final mean.
__global__ __launch_bounds__(1024) void k_loss_final(
    const float* __restrict__ predp, const float* __restrict__ hbias,
    const float* __restrict__ clean, float* __restrict__ out) {
  __shared__ float bl[64], ba[64];
  const int tid = threadIdx.x;
  const int w = tid >> 6, lane = tid & 63;
#pragma unroll
  for (int q = 0; q < 4; ++q) {
    const int b = w * 4 + q;
    float sd=0, sc=0, spc=0, sp=0;
#pragma unroll
    for (int e = 0; e < 8; ++e) {
      int o = e * 64 + lane;
      size_t idx = (size_t)b * D_OUT + o;
      float p = hbias[o];
#pragma unroll
      for (int k = 0; k < 16; ++k) p += predp[idx + (size_t)k * 32768];
      float c = clean[idx];
      float d = p - c;
      sd = fmaf(d,d,sd); sc = fmaf(c,c,sc);
      spc = fmaf(p,c,spc); sp = fmaf(p,p,sp);
    }
#pragma unroll
    for (int off = 32; off > 0; off >>= 1) {
      sd += __shfl_down(sd, off); sc += __shfl_down(sc, off);
      spc += __shfl_down(spc, off); sp += __shfl_down(sp, off);
    }
    if (lane == 0) {
      bl[b] = sd / (sc + 1e-6f);
      ba[b] = spc / ((sqrtf(sp) + 1e-6f) * (sqrtf(sc) + 1e-6f));
    }
  }
  __syncthreads();
  if (w == 0) {
    float l = bl[lane], a = ba[lane];
#pragma unroll
    for (int off = 32; off > 0; off >>= 1) {
      l += __shfl_down(l, off); a += __shfl_down(a, off);
    }
    if (lane == 0) {
      out[0] = l * (1.f / BATCH);
      out[1] = a * (1.f / BATCH);
    }
  }
}

extern "C" void kernel_launch(void* const* d_in, const int* in_sizes, int n_in,
                              void* d_out, int out_size, void* d_ws, size_t ws_size,
                              hipStream_t stream) {
  (void)in_sizes; (void)n_in; (void)out_size; (void)ws_size;
  const float* z     = (const float*)d_in[0];   // [16][64][512]
  const float* clean = (const float*)d_in[1];   // [64][512]
  const float* Wh    = (const float*)d_in[2];   // [1024][1024]
  const float* Wg    = (const float*)d_in[3];   // [1024][512]
  const float* bh    = (const float*)d_in[4];   // [1024]
  const float* gam   = (const float*)d_in[5];   // [1024]
  const float* bet   = (const float*)d_in[6];   // [1024]
  const float* alp   = (const float*)d_in[7];   // [1]
  const float* hW    = (const float*)d_in[8];   // [512][1024]
  const float* hbias = (const float*)d_in[9];   // [512]

  float* ws    = (float*)d_ws;
  float* hist  = ws;                          // 15*65536
  float* hbp   = hist + 15 * 65536;           // 16*65536
  float* zg    = hbp + 16 * 65536;            // 16*65536
  float* hfin  = zg + 16 * 65536;             // 65536
  float* predp = hfin + 65536;                // 16*32768
  float* WhT   = predp + 16 * 32768;          // 1024*1024
  float* WgT   = WhT + 1024 * 1024;           // 512*1024
  float* hWT   = WgT + 512 * 1024;            // 1024*512

  // one-time weight transposes (coalesced-read layouts)
  k_tr<<<dim3(16, 16), dim3(256), 0, stream>>>(Wh, WhT, 1024, 1024);
  k_tr<<<dim3(8, 16), dim3(256), 0, stream>>>(Wg, WgT, 1024, 512);
  k_tr<<<dim3(16, 8), dim3(256), 0, stream>>>(hW, hWT, 512, 1024);

  // all 16 z@Wg^T + bias, one fully-parallel launch (input-only)
  k_zg<<<dim3(4, 8, 16), dim3(256), 0, stream>>>(z, WgT, bh, zg);

#define REFINE_CASE(T) case T: \
    k_refine<T><<<dim3(64), dim3(256), 0, stream>>>( \
        hbp, zg + (size_t)T * 65536, hist, gam, bet, alp); break;

  // t = 0: h_prev == 0 -> h_base == zg[0]; no hbase launch at all
  k_refine<0><<<dim3(64), dim3(256), 0, stream>>>(hbp, zg, hist, gam, bet, alp);

  for (int t = 1; t < 15; ++t) {
    k_hbase<<<dim3(4, 8, 16), dim3(256), 0, stream>>>(
        hist + (size_t)(t - 1) * 65536, WhT, hbp);
    switch (t) {
      REFINE_CASE(1)  REFINE_CASE(2)  REFINE_CASE(3)  REFINE_CASE(4)
      REFINE_CASE(5)  REFINE_CASE(6)  REFINE_CASE(7)  REFINE_CASE(8)
      REFINE_CASE(9)  REFINE_CASE(10) REFINE_CASE(11) REFINE_CASE(12)
      REFINE_CASE(13) REFINE_CASE(14)
    }
  }
#undef REFINE_CASE

  k_hbase<<<dim3(4, 8, 16), dim3(256), 0, stream>>>(
      hist + (size_t)14 * 65536, WhT, hbp);
  k_refine_final<<<dim3(64), dim3(256), 0, stream>>>(
      hbp, zg + (size_t)15 * 65536, hist, hfin, gam, bet);
  k_head<<<dim3(2, 8, 16), dim3(256), 0, stream>>>(hfin, hWT, predp);
  k_loss_final<<<dim3(1), dim3(1024), 0, stream>>>(
      predp, hbias, clean, (float*)d_out);
}

// Round 9
// 425.095 us; speedup vs baseline: 1.6238x; 1.1355x over previous
//
#include <hip/hip_runtime.h>

#define D_G   512
#define D_H   1024
#define D_OUT 512
#define BATCH 64
#define LAMv  0.95f
#define ETAv  0.5f

// ---------------------------------------------------------------------------
// ws layout (floats):
//   hist : 15 * 65536    hbp : 16 * 65536    zg : 16 * 65536
//   hfin : 65536         predp: 16 * 32768   bvals: 128
//   WhT  : 1024*1024     WgT : 512*1024      hWT: 1024*512
// ---------------------------------------------------------------------------

__device__ inline float4 f4fma(float4 w, float s, float4 a) {
  a.x = fmaf(w.x, s, a.x); a.y = fmaf(w.y, s, a.y);
  a.z = fmaf(w.z, s, a.z); a.w = fmaf(w.w, s, a.w);
  return a;
}

// all three weight transposes in ONE dispatch. flat 512 blocks:
//   [0,256)  : Wh  1024x1024 -> WhT   (16 x, 16 y)
//   [256,384): Wg  1024x512  -> WgT   (8 x, 16 y)
//   [384,512): hW  512x1024  -> hWT   (16 x, 8 y)
__global__ __launch_bounds__(256) void k_tr3(const float* __restrict__ Wh,
                                             const float* __restrict__ Wg,
                                             const float* __restrict__ hW,
                                             float* __restrict__ WhT,
                                             float* __restrict__ WgT,
                                             float* __restrict__ hWT) {
  __shared__ float t[64][65];
  const int id = blockIdx.x;
  const float* src; float* dst; int R, C, bx, by;
  if (id < 256)      { src = Wh; dst = WhT; R = 1024; C = 1024;
                       bx = id & 15;        by = id >> 4; }
  else if (id < 384) { src = Wg; dst = WgT; R = 1024; C = 512;
                       bx = (id-256) & 7;   by = (id-256) >> 3; }
  else               { src = hW; dst = hWT; R = 512;  C = 1024;
                       bx = (id-384) & 15;  by = (id-384) >> 4; }
  const int c0 = bx * 64, r0 = by * 64;
  const int tid = threadIdx.x;
  const int lr = tid >> 4;            // 0..15
  const int lc = (tid & 15) * 4;      // 0,4,..,60
#pragma unroll
  for (int p = 0; p < 4; ++p) {
    int r = lr + p * 16;
    float4 v = *(const float4*)&src[(size_t)(r0 + r) * C + c0 + lc];
    t[r][lc] = v.x; t[r][lc+1] = v.y; t[r][lc+2] = v.z; t[r][lc+3] = v.w;
  }
  __syncthreads();
#pragma unroll
  for (int p = 0; p < 4; ++p) {
    int c = lr + p * 16;
    float4 v = make_float4(t[lc][c], t[lc+1][c], t[lc+2][c], t[lc+3][c]);
    *(float4*)&dst[(size_t)(c0 + c) * R + r0 + lc] = v;
  }
}

// zg[t][b][i] = z[t][b][:].Wg[i][:] + bh[i], via WgT (coalesced weights).
// grid (4 iq, 8 by, 16 t), 256 thr. Thread: 4 consecutive i, 2 batches.
__global__ __launch_bounds__(256) void k_zg(const float* __restrict__ z,
                                            const float* __restrict__ WgT,
                                            const float* __restrict__ bh,
                                            float* __restrict__ zg) {
  const int lane = threadIdx.x & 63;
  const int wid  = __builtin_amdgcn_readfirstlane(threadIdx.x >> 6);
  const int iq   = blockIdx.x * 64 + lane;      // i-quad index; i0 = 4*iq
  const int b0   = blockIdx.y * 8 + wid * 2;
  const int t    = blockIdx.z;
  const float4* w4  = (const float4*)WgT;       // [j][i]: idx jq*1024 + iq
  const float4* zr0 = (const float4*)(z + ((size_t)t * BATCH + b0) * D_G);
  const float4* zr1 = (const float4*)(z + ((size_t)t * BATCH + b0 + 1) * D_G);
  float4 A0 = {0,0,0,0}, A1 = {0,0,0,0};
#pragma unroll 2
  for (int jq = 0; jq < D_G / 4; ++jq) {
    float4 zv0 = zr0[jq], zv1 = zr1[jq];
    float4 wa = w4[(size_t)jq*1024 +       iq];
    float4 wb = w4[(size_t)jq*1024 + 256 + iq];
    float4 wc = w4[(size_t)jq*1024 + 512 + iq];
    float4 wd = w4[(size_t)jq*1024 + 768 + iq];
    A0 = f4fma(wa, zv0.x, A0); A0 = f4fma(wb, zv0.y, A0);
    A0 = f4fma(wc, zv0.z, A0); A0 = f4fma(wd, zv0.w, A0);
    A1 = f4fma(wa, zv1.x, A1); A1 = f4fma(wb, zv1.y, A1);
    A1 = f4fma(wc, zv1.z, A1); A1 = f4fma(wd, zv1.w, A1);
  }
  float4 bias = ((const float4*)bh)[iq];
  A0.x += bias.x; A0.y += bias.y; A0.z += bias.z; A0.w += bias.w;
  A1.x += bias.x; A1.y += bias.y; A1.z += bias.z; A1.w += bias.w;
  float4* o = (float4*)(zg + (size_t)t * (BATCH * D_H));
  o[(size_t)b0 * 256 + iq] = A0;
  o[(size_t)(b0 + 1) * 256 + iq] = A1;
}

// Partial h@Wh^T via WhT. grid (4 iq, 8 by, 16 k) = 512 blocks.
// outp[k][b][i] = sum_{j in k-th 1/16} WhT[j][i] * hprev[b][j]
__global__ __launch_bounds__(256) void k_hbase(const float* __restrict__ hprev,
                                               const float* __restrict__ WhT,
                                               float* __restrict__ outp) {
  const int lane = threadIdx.x & 63;
  const int wid  = __builtin_amdgcn_readfirstlane(threadIdx.x >> 6);
  const int iq   = blockIdx.x * 64 + lane;
  const int b0   = blockIdx.y * 8 + wid * 2;
  const int k    = blockIdx.z;                  // 1/16 of j-range (64 j)
  const float4* w4  = (const float4*)WhT;
  const float4* h0  = (const float4*)(hprev + (size_t)b0 * D_H);
  const float4* h1  = (const float4*)(hprev + (size_t)(b0 + 1) * D_H);
  float4 A0 = {0,0,0,0}, A1 = {0,0,0,0};
  const int jq0 = k * 16;
#pragma unroll 2
  for (int jq = jq0; jq < jq0 + 16; ++jq) {
    float4 hv0 = h0[jq], hv1 = h1[jq];
    float4 wa = w4[(size_t)jq*1024 +       iq];
    float4 wb = w4[(size_t)jq*1024 + 256 + iq];
    float4 wc = w4[(size_t)jq*1024 + 512 + iq];
    float4 wd = w4[(size_t)jq*1024 + 768 + iq];
    A0 = f4fma(wa, hv0.x, A0); A0 = f4fma(wb, hv0.y, A0);
    A0 = f4fma(wc, hv0.z, A0); A0 = f4fma(wd, hv0.w, A0);
    A1 = f4fma(wa, hv1.x, A1); A1 = f4fma(wb, hv1.y, A1);
    A1 = f4fma(wc, hv1.z, A1); A1 = f4fma(wd, hv1.w, A1);
  }
  float4* o = (float4*)(outp + (size_t)k * (BATCH * D_H));
  o[(size_t)b0 * 256 + iq] = A0;
  o[(size_t)(b0 + 1) * 256 + iq] = A1;
}

// wave-wide sum; result valid in lane 0
__device__ inline float wred(float x) {
#pragma unroll
  for (int off = 32; off > 0; off >>= 1) x += __shfl_down(x, off);
  return x;
}

// gated refinement, timestep T (0..14). One WG per batch, 256 thr (4 waves),
// 4 elems/thread. LN stats of the gated update computed analytically.
template<int T>
__global__ __launch_bounds__(256) void k_refine(
    const float* __restrict__ hbp, const float* __restrict__ zg,
    float* __restrict__ hist,
    const float* __restrict__ gamma, const float* __restrict__ beta,
    const float* __restrict__ alphap) {
  constexpr int TS = (T > 0) ? T : 1;
  __shared__ float lh[TS][D_H];          // history rows for this batch
  __shared__ float red[2][64];           // parity-alternated reduce scratch
  const int tid = threadIdx.x;
  const int b   = blockIdx.x;
  const int lane = tid & 63, w = tid >> 6;

  if constexpr (T > 0) {
    const float4* hist4 = (const float4*)hist;
    float4* lh4 = (float4*)lh;
#pragma unroll
    for (int s = 0; s < T; ++s)
      lh4[s * 256 + tid] = hist4[((size_t)s * BATCH + b) * 256 + tid];
  }

  float4 hb = ((const float4*)(zg + (size_t)b * D_H))[tid];
  if constexpr (T > 0) {                 // sum the 16 k-split Wh partials
    const float4* p = (const float4*)hbp;
    const size_t o = (size_t)b * 256 + tid;
#pragma unroll
    for (int k = 0; k < 16; ++k) {
      float4 pk = p[o + (size_t)k * 16384];
      hb.x += pk.x; hb.y += pk.y; hb.z += pk.z; hb.w += pk.w;
    }
  }
  const float4 gi = ((const float4*)gamma)[tid];
  const float4 bi = ((const float4*)beta)[tid];
  const float al = alphap[0];
  const float kk = (al >= 0.f) ? (1.f + log1pf(expf(al)))
                               : (1.f / (1.f + log1pf(expf(-al))));

  // pre-reduce (region 0): Shb, Shb2  (sync doubles as staging barrier)
  {
    float r0 = wred((hb.x + hb.y) + (hb.z + hb.w));
    float r1 = wred((hb.x*hb.x + hb.y*hb.y) + (hb.z*hb.z + hb.w*hb.w));
    if (lane == 0) { red[0][w] = r0; red[0][4 + w] = r1; }
  }
  __syncthreads();
  const float Shb  = (red[0][0] + red[0][1]) + (red[0][2] + red[0][3]);
  const float Shb2 = (red[0][4] + red[0][5]) + (red[0][6] + red[0][7]);
  float mu  = Shb * (1.f / D_H);
  float var = Shb2 * (1.f / D_H) - mu * mu;
  float rs  = rsqrtf(var + 1e-5f);
  float4 hc;
  hc.x = fmaxf(0.f, (hb.x - mu) * rs * gi.x + bi.x);
  hc.y = fmaxf(0.f, (hb.y - mu) * rs * gi.y + bi.y);
  hc.z = fmaxf(0.f, (hb.z - mu) * rs * gi.z + bi.z);
  hc.w = fmaxf(0.f, (hb.w - mu) * rs * gi.w + bi.w);

  if constexpr (T == 0) {
    // A == 0: Ah = 0 -> a_dyn = 0 -> h unchanged through all 3 iters
    ((float4*)(hist + (size_t)b * D_H))[tid] = hc;
    return;
  } else {
    const float4* lh4 = (const float4*)lh;
#pragma unroll 1
    for (int r = 0; r < 3; ++r) {
      // ---- d_s = h . h_s  (register partials -> region 1) ----
      float pd[T];
#pragma unroll
      for (int s = 0; s < T; ++s) {
        float4 lv = lh4[s * 256 + tid];
        pd[s] = (hc.x*lv.x + hc.y*lv.y) + (hc.z*lv.z + hc.w*lv.w);
      }
#pragma unroll
      for (int s = 0; s < T; ++s) {
        float t = wred(pd[s]);
        if (lane == 0) red[1][s * 4 + w] = t;
      }
      __syncthreads();
      float cf[T];
      {
        float lamc = ETAv;               // ETA * LAM^(T-1-s), s descending
#pragma unroll
        for (int s = T - 1; s >= 0; --s) {
          float ds = (red[1][s*4] + red[1][s*4+1])
                   + (red[1][s*4+2] + red[1][s*4+3]);
          cf[s] = lamc * ds;
          lamc *= LAMv;
        }
      }
      // ---- ah = sum_s cf[s] * h_s ----
      float4 ah = {0.f, 0.f, 0.f, 0.f};
#pragma unroll
      for (int s = 0; s < T; ++s) {
        float4 lv = lh4[s * 256 + tid];
        ah.x = fmaf(cf[s], lv.x, ah.x); ah.y = fmaf(cf[s], lv.y, ah.y);
        ah.z = fmaf(cf[s], lv.z, ah.z); ah.w = fmaf(cf[s], lv.w, ah.w);
      }
      // ---- single 5-value reduction (region 0) ----
      {
        float q0 = wred((hc.x*ah.x + hc.y*ah.y) + (hc.z*ah.z + hc.w*ah.w));
        float q1 = wred((hc.x*hc.x + hc.y*hc.y) + (hc.z*hc.z + hc.w*hc.w));
        float q2 = wred((ah.x*ah.x + ah.y*ah.y) + (ah.z*ah.z + ah.w*ah.w));
        float q3 = wred((hb.x*ah.x + hb.y*ah.y) + (hb.z*ah.z + hb.w*ah.w));
        float q4 = wred((ah.x + ah.y) + (ah.z + ah.w));
        if (lane == 0) {
          red[0][w] = q0; red[0][4+w] = q1; red[0][8+w] = q2;
          red[0][12+w] = q3; red[0][16+w] = q4;
        }
      }
      __syncthreads();
      float S_hAh  = (red[0][0]+red[0][1])+(red[0][2]+red[0][3]);
      float S_h2   = (red[0][4]+red[0][5])+(red[0][6]+red[0][7]);
      float S_Ah2  = (red[0][8]+red[0][9])+(red[0][10]+red[0][11]);
      float S_hbAh = (red[0][12]+red[0][13])+(red[0][14]+red[0][15]);
      float S_ah   = (red[0][16]+red[0][17])+(red[0][18]+red[0][19]);
      float n1 = sqrtf(S_h2) + 1e-6f;
      float n2 = sqrtf(S_Ah2) + 1e-6f;
      float R  = S_hAh / (n1 * n2 + 1e-6f);
      float Rp = fminf(fmaxf(R, 0.f), 1.f);
      float ad = 1.f - powf(1.f - Rp, kk);
      float oma = 1.f - ad * ad;
      float4 hn;
      hn.x = oma*hb.x + ad*ah.x; hn.y = oma*hb.y + ad*ah.y;
      hn.z = oma*hb.z + ad*ah.z; hn.w = oma*hb.w + ad*ah.w;
      float Shn  = oma * Shb + ad * S_ah;
      float Shn2 = oma*oma*Shb2 + 2.f*oma*ad*S_hbAh + ad*ad*S_Ah2;
      float mu2  = Shn * (1.f / D_H);
      float var2 = Shn2 * (1.f / D_H) - mu2 * mu2;
      float rs2  = rsqrtf(var2 + 1e-5f);
      hc.x = fmaxf(0.f, (hn.x - mu2) * rs2 * gi.x + bi.x);
      hc.y = fmaxf(0.f, (hn.y - mu2) * rs2 * gi.y + bi.y);
      hc.z = fmaxf(0.f, (hn.z - mu2) * rs2 * gi.z + bi.z);
      hc.w = fmaxf(0.f, (hn.w - mu2) * rs2 * gi.w + bi.w);
    }
    ((float4*)(hist + ((size_t)T * BATCH + b) * D_H))[tid] = hc;
  }
}

// final timestep: h = relu(LN(h_base + A@h)) x3, A = A_14 (rank 15).
__global__ __launch_bounds__(256) void k_refine_final(
    const float* __restrict__ hbp, const float* __restrict__ zg,
    const float* __restrict__ hist, float* __restrict__ hfin,
    const float* __restrict__ gamma, const float* __restrict__ beta) {
  __shared__ float lh[15][D_H];
  __shared__ float red[2][64];
  const int tid = threadIdx.x;
  const int b   = blockIdx.x;
  const int lane = tid & 63, w = tid >> 6;
  {
    const float4* hist4 = (const float4*)hist;
    float4* lh4 = (float4*)lh;
#pragma unroll
    for (int s = 0; s < 15; ++s)
      lh4[s * 256 + tid] = hist4[((size_t)s * BATCH + b) * 256 + tid];
  }
  float4 hb = ((const float4*)(zg + (size_t)b * D_H))[tid];
  {
    const float4* p = (const float4*)hbp;
    const size_t o = (size_t)b * 256 + tid;
#pragma unroll
    for (int k = 0; k < 16; ++k) {
      float4 pk = p[o + (size_t)k * 16384];
      hb.x += pk.x; hb.y += pk.y; hb.z += pk.z; hb.w += pk.w;
    }
  }
  const float4 gi = ((const float4*)gamma)[tid];
  const float4 bi = ((const float4*)beta)[tid];

  {
    float r0 = wred((hb.x + hb.y) + (hb.z + hb.w));
    float r1 = wred((hb.x*hb.x + hb.y*hb.y) + (hb.z*hb.z + hb.w*hb.w));
    if (lane == 0) { red[0][w] = r0; red[0][4 + w] = r1; }
  }
  __syncthreads();
  const float Shb  = (red[0][0] + red[0][1]) + (red[0][2] + red[0][3]);
  const float Shb2 = (red[0][4] + red[0][5]) + (red[0][6] + red[0][7]);
  float mu  = Shb * (1.f / D_H);
  float var = Shb2 * (1.f / D_H) - mu * mu;
  float rs  = rsqrtf(var + 1e-5f);
  float4 hc;
  hc.x = fmaxf(0.f, (hb.x - mu) * rs * gi.x + bi.x);
  hc.y = fmaxf(0.f, (hb.y - mu) * rs * gi.y + bi.y);
  hc.z = fmaxf(0.f, (hb.z - mu) * rs * gi.z + bi.z);
  hc.w = fmaxf(0.f, (hb.w - mu) * rs * gi.w + bi.w);

  const float4* lh4 = (const float4*)lh;
#pragma unroll 1
  for (int r = 0; r < 3; ++r) {
    float pd[15];
#pragma unroll
    for (int s = 0; s < 15; ++s) {
      float4 lv = lh4[s * 256 + tid];
      pd[s] = (hc.x*lv.x + hc.y*lv.y) + (hc.z*lv.z + hc.w*lv.w);
    }
#pragma unroll
    for (int s = 0; s < 15; ++s) {
      float t = wred(pd[s]);
      if (lane == 0) red[1][s * 4 + w] = t;
    }
    __syncthreads();
    float cf[15];
    {
      float lamc = ETAv;                 // ETA * LAM^(14-s), s descending
#pragma unroll
      for (int s = 14; s >= 0; --s) {
        float ds = (red[1][s*4] + red[1][s*4+1])
                 + (red[1][s*4+2] + red[1][s*4+3]);
        cf[s] = lamc * ds;
        lamc *= LAMv;
      }
    }
    float4 ah = {0.f, 0.f, 0.f, 0.f};
#pragma unroll
    for (int s = 0; s < 15; ++s) {
      float4 lv = lh4[s * 256 + tid];
      ah.x = fmaf(cf[s], lv.x, ah.x); ah.y = fmaf(cf[s], lv.y, ah.y);
      ah.z = fmaf(cf[s], lv.z, ah.z); ah.w = fmaf(cf[s], lv.w, ah.w);
    }
    {
      float q0 = wred((hb.x*ah.x + hb.y*ah.y) + (hb.z*ah.z + hb.w*ah.w));
      float q1 = wred((ah.x*ah.x + ah.y*ah.y) + (ah.z*ah.z + ah.w*ah.w));
      float q2 = wred((ah.x + ah.y) + (ah.z + ah.w));
      if (lane == 0) { red[0][w] = q0; red[0][4+w] = q1; red[0][8+w] = q2; }
    }
    __syncthreads();
    float S_hbAh = (red[0][0]+red[0][1])+(red[0][2]+red[0][3]);
    float S_Ah2  = (red[0][4]+red[0][5])+(red[0][6]+red[0][7]);
    float S_ah   = (red[0][8]+red[0][9])+(red[0][10]+red[0][11]);
    float4 hn;
    hn.x = hb.x + ah.x; hn.y = hb.y + ah.y;
    hn.z = hb.z + ah.z; hn.w = hb.w + ah.w;
    float Shn  = Shb + S_ah;
    float Shn2 = Shb2 + 2.f * S_hbAh + S_Ah2;
    float mu2  = Shn * (1.f / D_H);
    float var2 = Shn2 * (1.f / D_H) - mu2 * mu2;
    float rs2  = rsqrtf(var2 + 1e-5f);
    hc.x = fmaxf(0.f, (hn.x - mu2) * rs2 * gi.x + bi.x);
    hc.y = fmaxf(0.f, (hn.y - mu2) * rs2 * gi.y + bi.y);
    hc.z = fmaxf(0.f, (hn.z - mu2) * rs2 * gi.z + bi.z);
    hc.w = fmaxf(0.f, (hn.w - mu2) * rs2 * gi.w + bi.w);
  }
  ((float4*)(hfin + (size_t)b * D_H))[tid] = hc;
}

// Partial head via hWT [1024 j][512 o]. grid (2 oq, 8 by, 16 k), 256 thr.
__global__ __launch_bounds__(256) void k_head(const float* __restrict__ hfin,
                                              const float* __restrict__ hWT,
                                              float* __restrict__ predp) {
  const int lane = threadIdx.x & 63;
  const int wid  = __builtin_amdgcn_readfirstlane(threadIdx.x >> 6);
  const int oq   = blockIdx.x * 64 + lane;      // o-quad; o0 = 4*oq
  const int b0   = blockIdx.y * 8 + wid * 2;
  const int k    = blockIdx.z;
  const float4* w4 = (const float4*)hWT;        // idx jq*512 + oq
  const float4* h0 = (const float4*)(hfin + (size_t)b0 * D_H);
  const float4* h1 = (const float4*)(hfin + (size_t)(b0 + 1) * D_H);
  float4 A0 = {0,0,0,0}, A1 = {0,0,0,0};
  const int jq0 = k * 16;
#pragma unroll 2
  for (int jq = jq0; jq < jq0 + 16; ++jq) {
    float4 hv0 = h0[jq], hv1 = h1[jq];
    float4 wa = w4[(size_t)jq*512 +       oq];
    float4 wb = w4[(size_t)jq*512 + 128 + oq];
    float4 wc = w4[(size_t)jq*512 + 256 + oq];
    float4 wd = w4[(size_t)jq*512 + 384 + oq];
    A0 = f4fma(wa, hv0.x, A0); A0 = f4fma(wb, hv0.y, A0);
    A0 = f4fma(wc, hv0.z, A0); A0 = f4fma(wd, hv0.w, A0);
    A1 = f4fma(wa, hv1.x, A1); A1 = f4fma(wb, hv1.y, A1);
    A1 = f4fma(wc, hv1.z, A1); A1 = f4fma(wd, hv1.w, A1);
  }
  float4* o = (float4*)(predp + (size_t)k * (BATCH * D_OUT));
  o[(size_t)b0 * 128 + oq] = A0;
  o[(size_t)(b0 + 1) * 128 + oq] = A1;
}

// per-batch loss terms; ONE BLOCK PER BATCH (reads spread over 64 CUs).
// bvals[2b] = sq_err/denom, bvals[2b+1] = cosine.
__global__ __launch_bounds__(256) void k_loss_b(
    const float* __restrict__ predp, const float* __restrict__ hbias,
    const float* __restrict__ clean, float* __restrict__ bvals) {
  __shared__ float red[16];
  const int b = blockIdx.x;
  const int tid = threadIdx.x;
  const int lane = tid & 63, w = tid >> 6;
  float sd = 0, sc = 0, spc = 0, sp = 0;
#pragma unroll
  for (int e = 0; e < 2; ++e) {
    const int o = e * 256 + tid;
    const size_t idx = (size_t)b * D_OUT + o;
    float p = hbias[o];
#pragma unroll
    for (int k = 0; k < 16; ++k) p += predp[idx + (size_t)k * 32768];
    float c = clean[idx];
    float d = p - c;
    sd = fmaf(d, d, sd); sc = fmaf(c, c, sc);
    spc = fmaf(p, c, spc); sp = fmaf(p, p, sp);
  }
  sd = wred(sd); sc = wred(sc); spc = wred(spc); sp = wred(sp);
  if (lane == 0) {
    red[w] = sd; red[4 + w] = sc; red[8 + w] = spc; red[12 + w] = sp;
  }
  __syncthreads();
  if (tid == 0) {
    float Sd  = (red[0] + red[1]) + (red[2] + red[3]);
    float Sc  = (red[4] + red[5]) + (red[6] + red[7]);
    float Spc = (red[8] + red[9]) + (red[10] + red[11]);
    float Sp  = (red[12] + red[13]) + (red[14] + red[15]);
    bvals[b * 2 + 0] = Sd / (Sc + 1e-6f);
    bvals[b * 2 + 1] = Spc / ((sqrtf(Sp) + 1e-6f) * (sqrtf(Sc) + 1e-6f));
  }
}

// final mean over 64 batches; 1 block, 1 wave.
__global__ __launch_bounds__(64) void k_final(const float* __restrict__ bvals,
                                              float* __restrict__ out) {
  const int tid = threadIdx.x;
  float l = bvals[tid * 2 + 0];
  float a = bvals[tid * 2 + 1];
  l = wred(l); a = wred(a);
  if (tid == 0) { out[0] = l * (1.f / BATCH); out[1] = a * (1.f / BATCH); }
}

extern "C" void kernel_launch(void* const* d_in, const int* in_sizes, int n_in,
                              void* d_out, int out_size, void* d_ws, size_t ws_size,
                              hipStream_t stream) {
  (void)in_sizes; (void)n_in; (void)out_size; (void)ws_size;
  const float* z     = (const float*)d_in[0];   // [16][64][512]
  const float* clean = (const float*)d_in[1];   // [64][512]
  const float* Wh    = (const float*)d_in[2];   // [1024][1024]
  const float* Wg    = (const float*)d_in[3];   // [1024][512]
  const float* bh    = (const float*)d_in[4];   // [1024]
  const float* gam   = (const float*)d_in[5];   // [1024]
  const float* bet   = (const float*)d_in[6];   // [1024]
  const float* alp   = (const float*)d_in[7];   // [1]
  const float* hW    = (const float*)d_in[8];   // [512][1024]
  const float* hbias = (const float*)d_in[9];   // [512]

  float* ws    = (float*)d_ws;
  float* hist  = ws;                          // 15*65536
  float* hbp   = hist + 15 * 65536;           // 16*65536
  float* zg    = hbp + 16 * 65536;            // 16*65536
  float* hfin  = zg + 16 * 65536;             // 65536
  float* predp = hfin + 65536;                // 16*32768
  float* bvals = predp + 16 * 32768;          // 128
  float* WhT   = bvals + 128;                 // 1024*1024
  float* WgT   = WhT + 1024 * 1024;           // 512*1024
  float* hWT   = WgT + 512 * 1024;            // 1024*512

  // all three weight transposes, one dispatch
  k_tr3<<<dim3(512), dim3(256), 0, stream>>>(Wh, Wg, hW, WhT, WgT, hWT);

  // all 16 z@Wg^T + bias, one fully-parallel launch (input-only)
  k_zg<<<dim3(4, 8, 16), dim3(256), 0, stream>>>(z, WgT, bh, zg);

#define REFINE_CASE(T) case T: \
    k_refine<T><<<dim3(64), dim3(256), 0, stream>>>( \
        hbp, zg + (size_t)T * 65536, hist, gam, bet, alp); break;

  // t = 0: h_prev == 0 -> h_base == zg[0]; no hbase launch at all
  k_refine<0><<<dim3(64), dim3(256), 0, stream>>>(hbp, zg, hist, gam, bet, alp);

  for (int t = 1; t < 15; ++t) {
    k_hbase<<<dim3(4, 8, 16), dim3(256), 0, stream>>>(
        hist + (size_t)(t - 1) * 65536, WhT, hbp);
    switch (t) {
      REFINE_CASE(1)  REFINE_CASE(2)  REFINE_CASE(3)  REFINE_CASE(4)
      REFINE_CASE(5)  REFINE_CASE(6)  REFINE_CASE(7)  REFINE_CASE(8)
      REFINE_CASE(9)  REFINE_CASE(10) REFINE_CASE(11) REFINE_CASE(12)
      REFINE_CASE(13) REFINE_CASE(14)
    }
  }
#undef REFINE_CASE

  k_hbase<<<dim3(4, 8, 16), dim3(256), 0, stream>>>(
      hist + (size_t)14 * 65536, WhT, hbp);
  k_refine_final<<<dim3(64), dim3(256), 0, stream>>>(
      hbp, zg + (size_t)15 * 65536, hist, hfin, gam, bet);
  k_head<<<dim3(2, 8, 16), dim3(256), 0, stream>>>(hfin, hWT, predp);
  k_loss_b<<<dim3(64), dim3(256), 0, stream>>>(predp, hbias, clean, bvals);
  k_final<<<dim3(1), dim3(64), 0, stream>>>(bvals, (float*)d_out);
}